// Round 4
// baseline (783.271 us; speedup 1.0000x reference)
//
#include <hip/hip_runtime.h>

#define B_ROWS 1024
#define D_DIM  512
#define C_CLS  100000
#define N_TILES 782     // ceil(100000/128)
#define GRID_NJ 98      // 98*8 = 784 >= 782 (XCD-swizzle padding, 16 idle blocks)

typedef unsigned short u16;
typedef __attribute__((ext_vector_type(8))) short bf16x8;
typedef __attribute__((ext_vector_type(4))) float f32x4;

__device__ __forceinline__ u16 f2bf(float f) {
  unsigned u = __float_as_uint(f);
  u += 0x7fffu + ((u >> 16) & 1u);   // round-to-nearest-even
  return (u16)(u >> 16);
}

// pack 8 fp32 -> 8 bf16 (RTZ: take high 16 bits) via v_perm_b32
__device__ __forceinline__ bf16x8 pack8(float4 a, float4 b) {
  union { bf16x8 v; unsigned u[4]; } r;
  r.u[0] = __builtin_amdgcn_perm(__float_as_uint(a.y), __float_as_uint(a.x), 0x07060302u);
  r.u[1] = __builtin_amdgcn_perm(__float_as_uint(a.w), __float_as_uint(a.z), 0x07060302u);
  r.u[2] = __builtin_amdgcn_perm(__float_as_uint(b.y), __float_as_uint(b.x), 0x07060302u);
  r.u[3] = __builtin_amdgcn_perm(__float_as_uint(b.w), __float_as_uint(b.z), 0x07060302u);
  return r.v;
}

// One wave per row: L2-normalize a 512-float row, emit bf16 (features only).
__global__ void norm_feat_kernel(const float* __restrict__ in, u16* __restrict__ out)
{
  const int row  = blockIdx.x * 4 + (threadIdx.x >> 6);
  const int lane = threadIdx.x & 63;
  const float4* r = (const float4*)(in + (size_t)row * D_DIM);
  float4 v0 = r[lane];
  float4 v1 = r[lane + 64];
  float ss = v0.x*v0.x + v0.y*v0.y + v0.z*v0.z + v0.w*v0.w
           + v1.x*v1.x + v1.y*v1.y + v1.z*v1.z + v1.w*v1.w;
#pragma unroll
  for (int m = 1; m < 64; m <<= 1) ss += __shfl_xor(ss, m);
  const float inv = 1.0f / fmaxf(sqrtf(ss), 1e-12f);
  ushort4 o0, o1;
  o0.x = f2bf(v0.x * inv); o0.y = f2bf(v0.y * inv);
  o0.z = f2bf(v0.z * inv); o0.w = f2bf(v0.w * inv);
  o1.x = f2bf(v1.x * inv); o1.y = f2bf(v1.y * inv);
  o1.z = f2bf(v1.z * inv); o1.w = f2bf(v1.w * inv);
  ushort4* orow = (ushort4*)(out + (size_t)row * D_DIM);
  orow[lane]      = o0;
  orow[lane + 64] = o1;
}

// Barrier-free GEMM: no LDS in the K-loop. Each wave owns a 64x64 tile and
// loads A (bf16, L2-resident) and RAW fp32 W fragments straight from global
// in the (verified) 16x16x32 operand layout: row = l15, k-bytes = quad*16(A)
// / quad*32(W) -> 4 lanes x 16/32 B cover full 64B lines per row. W is packed
// fp32->bf16 in-register; per-row sum(w^2) accumulated along K and applied in
// the epilogue (cosine is scale-invariant) -> no W prep pass. 2-stage register
// ping-pong hides L2 latency under the 16-MFMA block; immediate k-offsets off
// 8 fixed base pointers keep address VALU ~0. Fused ArcFace margin + exp +
// per-row partial softmax-denominator.
__global__ __launch_bounds__(256, 2) void arc_gemm(
    const u16* __restrict__ fn, const float* __restrict__ wt,
    const int* __restrict__ targets, float* __restrict__ psum,
    float* __restrict__ tlogit)
{
  const int tid = threadIdx.x;
  const int bx  = blockIdx.x;
  // XCD-aware: bx%8 = XCD (round-robin dispatch); 8 consecutive blocks on one
  // XCD share tile_n -> W tile fetched beyond-L2 once, reused 8x from L2.
  const int xcd = bx & 7;
  const int l   = bx >> 3;
  const int tile_ni = (l >> 3) * 8 + xcd;
  if (tile_ni >= N_TILES) return;
  const int tile_m = (l & 7) << 7;
  const int tile_n = tile_ni << 7;

  const int wave = tid >> 6, lane = tid & 63;
  const int wm = wave >> 1, wno = wave & 1;
  const int quad = lane >> 4, l15 = lane & 15;

  // fragment base pointers (k-immediates do the rest)
  const u16*   Ab[4];
  const float* Wb[4];
#pragma unroll
  for (int r = 0; r < 4; r++) {
    Ab[r] = fn + (size_t)(tile_m + wm * 64 + r * 16 + l15) * D_DIM + quad * 8;
    const int wr = tile_n + wno * 64 + r * 16 + l15;   // clamp pad rows
    Wb[r] = wt + (size_t)min(wr, C_CLS - 1) * D_DIM + quad * 8;
  }

  f32x4 acc[4][4] = {};
  float ssq[4] = {0.f, 0.f, 0.f, 0.f};

  bf16x8 a[2][4];
  float4 w[2][4][2];

  // prologue: stage k0 = 0
#pragma unroll
  for (int r = 0; r < 4; r++) {
    a[0][r]    = *(const bf16x8*)(Ab[r]);
    w[0][r][0] = *(const float4*)(Wb[r]);
    w[0][r][1] = *(const float4*)(Wb[r] + 4);
  }

#pragma unroll
  for (int i = 0; i < 16; ++i) {
    const int cur = i & 1, nxt = cur ^ 1;
    if (i < 15) {               // prefetch iter i+1 into the other buffer
      const int k0 = (i + 1) * 32;
#pragma unroll
      for (int r = 0; r < 4; r++) {
        a[nxt][r]    = *(const bf16x8*)(Ab[r] + k0);
        w[nxt][r][0] = *(const float4*)(Wb[r] + k0);
        w[nxt][r][1] = *(const float4*)(Wb[r] + k0 + 4);
      }
    }
    bf16x8 wf[4];
#pragma unroll
    for (int r = 0; r < 4; r++) {
      const float4 x = w[cur][r][0], y = w[cur][r][1];
      ssq[r] += x.x*x.x + x.y*x.y + x.z*x.z + x.w*x.w
              + y.x*y.x + y.y*y.y + y.z*y.z + y.w*y.w;
      wf[r] = pack8(x, y);
    }
#pragma unroll
    for (int rm = 0; rm < 4; rm++)
#pragma unroll
      for (int rn = 0; rn < 4; rn++)
        acc[rm][rn] = __builtin_amdgcn_mfma_f32_16x16x32_bf16(
            a[cur][rm], wf[rn], acc[rm][rn], 0, 0, 0);
  }

  // per-W-row 1/||w||: lane holds partial over its quad's 128 k-elements;
  // lanes with equal l15 across the 4 quads are xor-16/32 apart.
  float wiv[4];
#pragma unroll
  for (int r = 0; r < 4; r++) {
    float s = ssq[r];
    s += __shfl_xor(s, 16);
    s += __shfl_xor(s, 32);
    wiv[r] = 1.0f / fmaxf(sqrtf(s), 1e-12f);
  }

  // Epilogue: logits = 30*cos (target col: 30*phi); accumulate exp(l-30).
  const float Sc   = 30.0f;
  const float COSM = 0.9553364891256060f;
  const float SINM = 0.2955202066613396f;
  const float THc  = -0.9553364891256060f;
  const float MMc  = 0.0886560619984019f;

#pragma unroll
  for (int rm = 0; rm < 4; rm++) {
#pragma unroll
    for (int reg = 0; reg < 4; reg++) {
      const int bl = wm * 64 + rm * 16 + quad * 4 + reg;  // C/D row = M index
      const int b = tile_m + bl;
      const int tgt = targets[b];   // same addr across the 16-lane group: broadcast
      float s = 0.0f;
#pragma unroll
      for (int rn = 0; rn < 4; rn++) {
        const int c = tile_n + wno * 64 + rn * 16 + l15;  // C/D col = N index
        const float cosv = acc[rm][rn][reg] * wiv[rn];
        float logit = Sc * cosv;
        if (c == tgt) {
          const float sine = sqrtf(fmaxf(1.0f - cosv * cosv, 0.0f));
          float phi = cosv * COSM - sine * SINM;
          phi = (cosv > THc) ? phi : (cosv - MMc);
          logit = Sc * phi;
          tlogit[b] = logit;   // exactly one lane in the grid owns (b, tgt)
        }
        s += (c < C_CLS) ? __expf(logit - 30.0f) : 0.0f;  // mask pad columns
      }
      s += __shfl_xor(s, 1);
      s += __shfl_xor(s, 2);
      s += __shfl_xor(s, 4);
      s += __shfl_xor(s, 8);
      if (l15 == 0) atomicAdd(psum + b, s);
    }
  }
}

__global__ void finalize_loss(const float* __restrict__ psum,
                              const float* __restrict__ tlogit,
                              float* __restrict__ out)
{
  const int tid = threadIdx.x;
  float s = 0.0f;
  for (int i = tid; i < B_ROWS; i += 256)
    s += 30.0f + logf(psum[i]) - tlogit[i];   // logsumexp - target logit
#pragma unroll
  for (int m = 1; m < 64; m <<= 1) s += __shfl_xor(s, m);
  __shared__ float red[4];
  if ((tid & 63) == 0) red[tid >> 6] = s;
  __syncthreads();
  if (tid == 0) out[0] = (red[0] + red[1] + red[2] + red[3]) * (1.0f / B_ROWS);
}

extern "C" void kernel_launch(void* const* d_in, const int* in_sizes, int n_in,
                              void* d_out, int out_size, void* d_ws, size_t ws_size,
                              hipStream_t stream) {
  const float* feat = (const float*)d_in[0];
  const float* wt   = (const float*)d_in[1];
  const int*   tgt  = (const int*)d_in[2];
  float* out = (float*)d_out;
  char* ws = (char*)d_ws;

  // ws layout: fn 1 MB | psum 4 KB | tlogit 4 KB
  u16* fn = (u16*)ws;
  float* psum = (float*)(ws + (size_t)B_ROWS * D_DIM * 2);
  float* tlogit = psum + B_ROWS;

  hipMemsetAsync(psum, 0, B_ROWS * sizeof(float), stream);
  norm_feat_kernel<<<B_ROWS / 4, 256, 0, stream>>>(feat, fn);
  arc_gemm<<<GRID_NJ * 8 * 8, 256, 0, stream>>>(fn, wt, tgt, psum, tlogit);
  finalize_loss<<<1, 256, 0, stream>>>(psum, tlogit, out);
}

// Round 5
// 508.499 us; speedup vs baseline: 1.5404x; 1.5404x over previous
//
#include <hip/hip_runtime.h>

#define B_ROWS 1024
#define D_DIM  512
#define C_CLS  100000
#define N_TILES 782     // ceil(100000/128)
#define GRID_NJ 98      // 98*8 = 784 >= 782 (XCD-swizzle padding, 16 idle blocks)

typedef unsigned short u16;
typedef __attribute__((ext_vector_type(8))) short bf16x8;
typedef __attribute__((ext_vector_type(4))) float f32x4;

__device__ __forceinline__ u16 f2bf(float f) {
  unsigned u = __float_as_uint(f);
  u += 0x7fffu + ((u >> 16) & 1u);   // round-to-nearest-even
  return (u16)(u >> 16);
}

// pack 8 fp32 -> 8 bf16 (RTZ: take high 16 bits) via v_perm_b32
__device__ __forceinline__ bf16x8 pack8(float4 a, float4 b) {
  union { bf16x8 v; unsigned u[4]; } r;
  r.u[0] = __builtin_amdgcn_perm(__float_as_uint(a.y), __float_as_uint(a.x), 0x07060302u);
  r.u[1] = __builtin_amdgcn_perm(__float_as_uint(a.w), __float_as_uint(a.z), 0x07060302u);
  r.u[2] = __builtin_amdgcn_perm(__float_as_uint(b.y), __float_as_uint(b.x), 0x07060302u);
  r.u[3] = __builtin_amdgcn_perm(__float_as_uint(b.w), __float_as_uint(b.z), 0x07060302u);
  return r.v;
}

__device__ __forceinline__ void gll16(const void* g, void* l) {
  __builtin_amdgcn_global_load_lds(
      (const __attribute__((address_space(1))) unsigned int*)g,
      (__attribute__((address_space(3))) unsigned int*)l, 16, 0, 0);
}

// One wave per row: L2-normalize a 512-float row, emit bf16 (features only).
__global__ void norm_feat_kernel(const float* __restrict__ in, u16* __restrict__ out)
{
  const int row  = blockIdx.x * 4 + (threadIdx.x >> 6);
  const int lane = threadIdx.x & 63;
  const float4* r = (const float4*)(in + (size_t)row * D_DIM);
  float4 v0 = r[lane];
  float4 v1 = r[lane + 64];
  float ss = v0.x*v0.x + v0.y*v0.y + v0.z*v0.z + v0.w*v0.w
           + v1.x*v1.x + v1.y*v1.y + v1.z*v1.z + v1.w*v1.w;
#pragma unroll
  for (int m = 1; m < 64; m <<= 1) ss += __shfl_xor(ss, m);
  const float inv = 1.0f / fmaxf(sqrtf(ss), 1e-12f);
  ushort4 o0, o1;
  o0.x = f2bf(v0.x * inv); o0.y = f2bf(v0.y * inv);
  o0.z = f2bf(v0.z * inv); o0.w = f2bf(v0.w * inv);
  o1.x = f2bf(v1.x * inv); o1.y = f2bf(v1.y * inv);
  o1.z = f2bf(v1.z * inv); o1.w = f2bf(v1.w * inv);
  ushort4* orow = (ushort4*)(out + (size_t)row * D_DIM);
  orow[lane]      = o0;
  orow[lane + 64] = o1;
}

// Round-3 double-buffered one-barrier K-loop + fused W fp32->bf16 conversion:
//   barrier -> gll16 A(k+1) + global fp32 W(k+1) loads -> ds_read(buf k)
//   -> 16 MFMA -> ssq/pack W(k+1) -> ds_write Ws[k+1 buf]
// W loads fly over the ds_read+MFMA block (~400 cyc), so the conversion adds
// VALU but no latency to the critical path. Per-row sum(w^2) along K; 1/||w||
// applied in the epilogue (cosine is scale-invariant) -> no W prep pass.
// Fused ArcFace margin + exp + per-row partial softmax-denominator.
__global__ __launch_bounds__(256, 4) void arc_gemm(
    const u16* __restrict__ fn, const float* __restrict__ wt,
    const int* __restrict__ targets, float* __restrict__ psum,
    float* __restrict__ tlogit)
{
  __shared__ u16 As[2][4096];   // 128 rows x 32 k (bf16), double-buffered
  __shared__ u16 Ws[2][4096];
  __shared__ float winv[128];

  const int tid = threadIdx.x;
  const int bx  = blockIdx.x;
  // XCD-aware: bx%8 = XCD (round-robin dispatch); 8 consecutive blocks on one
  // XCD share tile_n -> W tile fetched beyond-L2 once, reused 8x from L2.
  const int xcd = bx & 7;
  const int l   = bx >> 3;
  const int tile_ni = (l >> 3) * 8 + xcd;
  if (tile_ni >= N_TILES) return;
  const int tile_m = (l & 7) << 7;
  const int tile_n = tile_ni << 7;

  const int wave = tid >> 6, lane = tid & 63;
  const int wm = wave >> 1, wno = wave & 1;
  const int quad = lane >> 4, l15 = lane & 15;

  f32x4 acc[4][4] = {};

  // Staging thread t owns rows (t>>2, t>>2+64); XOR k-chunk swizzle:
  // LDS slot (row, s) holds global chunk s ^ ((row>>1)&3) -> 2-way (free)
  // bank aliasing on ds_read_b128 instead of 8-way; gll16 dest stays linear.
  const int srow   = tid >> 2;
  const int schunk = (tid & 3) ^ ((tid >> 3) & 3);
  const u16* Ag = fn + (size_t)(tile_m + srow) * D_DIM + schunk * 8;
  const int wr0 = tile_n + srow;
  // clamp pad rows (tile 781 extends past 100000); masked in epilogue anyway
  const float* Wg0 = wt + (size_t)min(wr0, C_CLS - 1) * D_DIM + schunk * 8;
  const float* Wg1 = wt + (size_t)min(wr0 + 64, C_CLS - 1) * D_DIM + schunk * 8;
  const int ldst = tid * 8;   // u16 offset of this thread's 16B LDS slot

  // read-side swizzle: (row>>1)&3 == (l15>>1)&3 (r*16, wm*64 are 0 mod 8)
  const int rsw = (quad ^ ((l15 >> 1) & 3)) * 8;
  const int ra  = (wm * 64 + l15) * 32 + rsw;
  const int rw  = (wno * 64 + l15) * 32 + rsw;

  float ssq0 = 0.0f, ssq1 = 0.0f;

  // prologue: stage k=0 into buffer 0 (A via gll16; W via reg pack)
  gll16(Ag,              &As[0][ldst]);
  gll16(Ag + 64 * D_DIM, &As[0][2048 + ldst]);
  {
    const float4 wa = *(const float4*)(Wg0);
    const float4 wb = *(const float4*)(Wg0 + 4);
    const float4 wc = *(const float4*)(Wg1);
    const float4 wd = *(const float4*)(Wg1 + 4);
    ssq0 += wa.x*wa.x + wa.y*wa.y + wa.z*wa.z + wa.w*wa.w
          + wb.x*wb.x + wb.y*wb.y + wb.z*wb.z + wb.w*wb.w;
    ssq1 += wc.x*wc.x + wc.y*wc.y + wc.z*wc.z + wc.w*wc.w
          + wd.x*wd.x + wd.y*wd.y + wd.z*wd.z + wd.w*wd.w;
    *(bf16x8*)&Ws[0][ldst]        = pack8(wa, wb);
    *(bf16x8*)&Ws[0][2048 + ldst] = pack8(wc, wd);
  }

#pragma unroll
  for (int i = 0; i < 16; ++i) {
    __syncthreads();   // As/Ws[i&1] ready (drains vmcnt+lgkmcnt; syncs block)
    float4 wa, wb, wc, wd;
    const int nb = (i + 1) & 1;
    if (i < 15) {      // prefetch k+1: A -> LDS direct, W fp32 -> registers
      const int kn = (i + 1) * 32;
      gll16(Ag + kn,              &As[nb][ldst]);
      gll16(Ag + 64 * D_DIM + kn, &As[nb][2048 + ldst]);
      wa = *(const float4*)(Wg0 + kn);
      wb = *(const float4*)(Wg0 + kn + 4);
      wc = *(const float4*)(Wg1 + kn);
      wd = *(const float4*)(Wg1 + kn + 4);
    }
    const int cb = i & 1;
    bf16x8 af[4], wf[4];
#pragma unroll
    for (int r = 0; r < 4; r++) af[r] = *(const bf16x8*)&As[cb][ra + r * 16 * 32];
#pragma unroll
    for (int r = 0; r < 4; r++) wf[r] = *(const bf16x8*)&Ws[cb][rw + r * 16 * 32];
#pragma unroll
    for (int rm = 0; rm < 4; rm++)
#pragma unroll
      for (int rn = 0; rn < 4; rn++)
        acc[rm][rn] = __builtin_amdgcn_mfma_f32_16x16x32_bf16(
            af[rm], wf[rn], acc[rm][rn], 0, 0, 0);
    if (i < 15) {      // consume the W prefetch: ssq + pack into next buffer
      ssq0 += wa.x*wa.x + wa.y*wa.y + wa.z*wa.z + wa.w*wa.w
            + wb.x*wb.x + wb.y*wb.y + wb.z*wb.z + wb.w*wb.w;
      ssq1 += wc.x*wc.x + wc.y*wc.y + wc.z*wc.z + wc.w*wc.w
            + wd.x*wd.x + wd.y*wd.y + wd.z*wd.z + wd.w*wd.w;
      *(bf16x8*)&Ws[nb][ldst]        = pack8(wa, wb);
      *(bf16x8*)&Ws[nb][2048 + ldst] = pack8(wc, wd);
    }
  }

  // per-row 1/||w||: reduce ssq over the 4 chunk-threads (consecutive lanes)
  ssq0 += __shfl_xor(ssq0, 1); ssq0 += __shfl_xor(ssq0, 2);
  ssq1 += __shfl_xor(ssq1, 1); ssq1 += __shfl_xor(ssq1, 2);
  if ((tid & 3) == 0) {
    winv[srow]      = 1.0f / fmaxf(sqrtf(ssq0), 1e-12f);
    winv[srow + 64] = 1.0f / fmaxf(sqrtf(ssq1), 1e-12f);
  }
  __syncthreads();

  float wiv[4];
#pragma unroll
  for (int rn = 0; rn < 4; rn++) wiv[rn] = winv[wno * 64 + rn * 16 + l15];

  // Epilogue: logits = 30*cos (target col: 30*phi); accumulate exp(l-30).
  const float Sc   = 30.0f;
  const float COSM = 0.9553364891256060f;
  const float SINM = 0.2955202066613396f;
  const float THc  = -0.9553364891256060f;
  const float MMc  = 0.0886560619984019f;

#pragma unroll
  for (int rm = 0; rm < 4; rm++) {
#pragma unroll
    for (int reg = 0; reg < 4; reg++) {
      const int bl = wm * 64 + rm * 16 + quad * 4 + reg;  // C/D row = M index
      const int b = tile_m + bl;
      const int tgt = targets[b];   // uniform across 16-lane group: broadcast
      float s = 0.0f;
#pragma unroll
      for (int rn = 0; rn < 4; rn++) {
        const int c = tile_n + wno * 64 + rn * 16 + l15;  // C/D col = N index
        const float cosv = acc[rm][rn][reg] * wiv[rn];
        float logit = Sc * cosv;
        if (c == tgt) {
          const float sine = sqrtf(fmaxf(1.0f - cosv * cosv, 0.0f));
          float phi = cosv * COSM - sine * SINM;
          phi = (cosv > THc) ? phi : (cosv - MMc);
          logit = Sc * phi;
          tlogit[b] = logit;   // exactly one lane in the grid owns (b, tgt)
        }
        s += (c < C_CLS) ? __expf(logit - 30.0f) : 0.0f;  // mask pad columns
      }
      s += __shfl_xor(s, 1);
      s += __shfl_xor(s, 2);
      s += __shfl_xor(s, 4);
      s += __shfl_xor(s, 8);
      if (l15 == 0) atomicAdd(psum + b, s);
    }
  }
}

__global__ void finalize_loss(const float* __restrict__ psum,
                              const float* __restrict__ tlogit,
                              float* __restrict__ out)
{
  const int tid = threadIdx.x;
  float s = 0.0f;
  for (int i = tid; i < B_ROWS; i += 256)
    s += 30.0f + logf(psum[i]) - tlogit[i];   // logsumexp - target logit
#pragma unroll
  for (int m = 1; m < 64; m <<= 1) s += __shfl_xor(s, m);
  __shared__ float red[4];
  if ((tid & 63) == 0) red[tid >> 6] = s;
  __syncthreads();
  if (tid == 0) out[0] = (red[0] + red[1] + red[2] + red[3]) * (1.0f / B_ROWS);
}

extern "C" void kernel_launch(void* const* d_in, const int* in_sizes, int n_in,
                              void* d_out, int out_size, void* d_ws, size_t ws_size,
                              hipStream_t stream) {
  const float* feat = (const float*)d_in[0];
  const float* wt   = (const float*)d_in[1];
  const int*   tgt  = (const int*)d_in[2];
  float* out = (float*)d_out;
  char* ws = (char*)d_ws;

  // ws layout: fn 1 MB | psum 4 KB | tlogit 4 KB
  u16* fn = (u16*)ws;
  float* psum = (float*)(ws + (size_t)B_ROWS * D_DIM * 2);
  float* tlogit = psum + B_ROWS;

  hipMemsetAsync(psum, 0, B_ROWS * sizeof(float), stream);
  norm_feat_kernel<<<B_ROWS / 4, 256, 0, stream>>>(feat, fn);
  arc_gemm<<<GRID_NJ * 8 * 8, 256, 0, stream>>>(fn, wt, tgt, psum, tlogit);
  finalize_loss<<<1, 256, 0, stream>>>(psum, tlogit, out);
}